// Round 5
// baseline (350.235 us; speedup 1.0000x reference)
//
#include <hip/hip_runtime.h>
#include <hip/hip_bf16.h>
#include <math.h>

#define D_MODEL 1024
#define SEQ 1024
#define BATCH 16
#define NROWS (BATCH * SEQ)   // 16384
#define KTILES 16             // D_MODEL / 64

typedef __bf16 bf16x8 __attribute__((ext_vector_type(8)));
typedef __bf16 bf16x4 __attribute__((ext_vector_type(4)));
typedef float f32x4 __attribute__((ext_vector_type(4)));
typedef __hip_bfloat16 bf16;

__device__ __forceinline__ float bf2f(bf16 v) { return __bfloat162float(v); }
__device__ __forceinline__ bf16 f2bf(float v) { return __float2bfloat16(v); }

__device__ __forceinline__ void gload_lds16(const bf16* g, bf16* l) {
    __builtin_amdgcn_global_load_lds(
        (const __attribute__((address_space(1))) void*)g,
        (__attribute__((address_space(3))) void*)l, 16, 0, 0);
}

#define VM_WAIT(n)   asm volatile("s_waitcnt vmcnt(" #n ")" ::: "memory")
#define LGKM_WAIT(n) asm volatile("s_waitcnt lgkmcnt(" #n ")" ::: "memory")
#define BAR()        __builtin_amdgcn_s_barrier()

// 256 blocks -> 8 XCDs x 32. Each XCD: 8 M-bands x 4 N-tiles concurrent.
__device__ __forceinline__ void tile_coords256(int lin, int& m0, int& n0) {
    const int xcd = lin & 7;
    const int loc = lin >> 3;            // 0..31
    m0 = (xcd * 8 + (loc >> 2)) * 256;
    n0 = (loc & 3) * 256;
}

// ---------------- all 4 weights fp32 -> bf16, one dispatch (vectorized) ----------------
__global__ void conv_w4_kernel(const float* __restrict__ s0, const float* __restrict__ s1,
                               const float* __restrict__ s2, const float* __restrict__ s3,
                               bf16* __restrict__ dst) {
    const float* srcs[4] = {s0, s1, s2, s3};
    const float* src = srcs[blockIdx.y];
    bf16* d = dst + (size_t)blockIdx.y * (D_MODEL * D_MODEL);
    int i = blockIdx.x * blockDim.x + threadIdx.x;
    const int stride = gridDim.x * blockDim.x;
    for (; i < (D_MODEL * D_MODEL) / 4; i += stride) {
        float4 f = reinterpret_cast<const float4*>(src)[i];
        bf16x4 o;
        o[0] = (__bf16)f.x; o[1] = (__bf16)f.y; o[2] = (__bf16)f.z; o[3] = (__bf16)f.w;
        reinterpret_cast<bf16x4*>(d)[i] = o;
    }
}

// ---------------- fused LayerNorm + time-mix: one wave per row ----------------
// XCD-banded block swizzle: consecutive rows stay on one XCD so the prev-row
// re-read (row t-1 fetched by both block b and b-1) hits that XCD's L2.
__global__ __launch_bounds__(256) void lnmix_kernel(
    const float* __restrict__ x, const float* __restrict__ gamma, const float* __restrict__ beta,
    const float* __restrict__ tmk, const float* __restrict__ tmv, const float* __restrict__ tmr,
    bf16* __restrict__ xk, bf16* __restrict__ xv, bf16* __restrict__ xr)
{
    const int wave = threadIdx.x >> 6, lane = threadIdx.x & 63;
    const int lb = (blockIdx.x & 7) * (gridDim.x >> 3) + (blockIdx.x >> 3);
    const int row = lb * 4 + wave;
    const int t = row & (SEQ - 1);
    const size_t base = (size_t)row * D_MODEL;

    float4 vc[4], vp[4];
    float sc = 0.f, sc2 = 0.f, sp = 0.f, sp2 = 0.f;
#pragma unroll
    for (int c = 0; c < 4; c++) {
        const int d = lane * 4 + c * 256;
        vc[c] = *reinterpret_cast<const float4*>(x + base + d);
        if (t == 0) { vp[c] = make_float4(0.f, 0.f, 0.f, 0.f); }
        else        { vp[c] = *reinterpret_cast<const float4*>(x + base - D_MODEL + d); }
        sc  += vc[c].x + vc[c].y + vc[c].z + vc[c].w;
        sc2 += vc[c].x * vc[c].x + vc[c].y * vc[c].y + vc[c].z * vc[c].z + vc[c].w * vc[c].w;
        sp  += vp[c].x + vp[c].y + vp[c].z + vp[c].w;
        sp2 += vp[c].x * vp[c].x + vp[c].y * vp[c].y + vp[c].z * vp[c].z + vp[c].w * vp[c].w;
    }
#pragma unroll
    for (int off = 1; off < 64; off <<= 1) {
        sc  += __shfl_xor(sc, off);
        sc2 += __shfl_xor(sc2, off);
        sp  += __shfl_xor(sp, off);
        sp2 += __shfl_xor(sp2, off);
    }
    const float muc = sc * (1.0f / D_MODEL);
    const float rc  = rsqrtf(sc2 * (1.0f / D_MODEL) - muc * muc + 1e-5f);
    const float mup = sp * (1.0f / D_MODEL);
    const float rp  = rsqrtf(sp2 * (1.0f / D_MODEL) - mup * mup + 1e-5f);

#pragma unroll
    for (int c = 0; c < 4; c++) {
        const int d = lane * 4 + c * 256;
        float4 g  = *reinterpret_cast<const float4*>(gamma + d);
        float4 b  = *reinterpret_cast<const float4*>(beta + d);
        float4 mk = *reinterpret_cast<const float4*>(tmk + d);
        float4 mv = *reinterpret_cast<const float4*>(tmv + d);
        float4 mr = *reinterpret_cast<const float4*>(tmr + d);
        float cn[4], pn[4];
        cn[0] = (vc[c].x - muc) * rc * g.x + b.x;
        cn[1] = (vc[c].y - muc) * rc * g.y + b.y;
        cn[2] = (vc[c].z - muc) * rc * g.z + b.z;
        cn[3] = (vc[c].w - muc) * rc * g.w + b.w;
        if (t == 0) { pn[0] = pn[1] = pn[2] = pn[3] = 0.f; }
        else {
            pn[0] = (vp[c].x - mup) * rp * g.x + b.x;
            pn[1] = (vp[c].y - mup) * rp * g.y + b.y;
            pn[2] = (vp[c].z - mup) * rp * g.z + b.z;
            pn[3] = (vp[c].w - mup) * rp * g.w + b.w;
        }
        const float mkv[4] = {mk.x, mk.y, mk.z, mk.w};
        const float mvv[4] = {mv.x, mv.y, mv.z, mv.w};
        const float mrv[4] = {mr.x, mr.y, mr.z, mr.w};
        bf16x4 ok, ov, orr;
#pragma unroll
        for (int e = 0; e < 4; e++) {
            ok[e]  = (__bf16)(mkv[e] * cn[e] + (1.0f - mkv[e]) * pn[e]);
            ov[e]  = (__bf16)(mvv[e] * cn[e] + (1.0f - mvv[e]) * pn[e]);
            orr[e] = (__bf16)(mrv[e] * cn[e] + (1.0f - mrv[e]) * pn[e]);
        }
        *reinterpret_cast<bf16x4*>(xk + base + d) = ok;
        *reinterpret_cast<bf16x4*>(xv + base + d) = ov;
        *reinterpret_cast<bf16x4*>(xr + base + d) = orr;
    }
}

// ============================================================================
// 256x256 GEMM core, BK=64, 8 waves (2Mx4N), cross-phase fragment prefetch.
// R5 change: PRECOMPUTED FRAGMENT POINTERS. Only 4 lane-dependent LDS offsets
// exist (co_ks = ((ks*4+quad)^(mf&7))*8 for A and B); they are computed once
// and every fragment read is ds_read_b128 [ptr], offset:imm with the R-index
// (R*2048B) and dbuf select (cur*32768B, compile-time under unroll 2) folded
// into the immediate. Eliminates all per-read VALU from the read windows.
// ============================================================================
__device__ __forceinline__ void gemm256_core(
    const bf16* __restrict__ A, const bf16* __restrict__ W,
    bf16* __restrict__ AsB, bf16* __restrict__ BsB,
    int m0, int n0, f32x4 (&acc)[8][4])
{
    const int tid  = threadIdx.x;
    const int wave = tid >> 6, lane = tid & 63;
    const int wm = wave >> 2, wn = wave & 3;
    const int mf = lane & 15, quad = lane >> 4;
    const int srow = tid >> 3;                       // 0..63
    const int scol = ((tid & 7) ^ (srow & 7)) * 8;   // pre-swizzled source chunk
    const int dsub = wave * 512;                     // wave-uniform LDS dest base

    const bf16* Ag = A + (size_t)(m0 + srow) * D_MODEL + scol;
    const bf16* Bg = W + (size_t)(n0 + srow) * D_MODEL + scol;

    // precomputed fragment base pointers (one per k-slot, per matrix)
    const int co0 = (quad ^ (mf & 7)) * 8;
    const int co1 = ((4 + quad) ^ (mf & 7)) * 8;
    const bf16* aP0 = AsB + wm * 8192 + mf * 64 + co0;
    const bf16* aP1 = AsB + wm * 8192 + mf * 64 + co1;
    const bf16* bP0 = BsB + wn * 4096 + mf * 64 + co0;
    const bf16* bP1 = BsB + wn * 4096 + mf * 64 + co1;

#define RDA(cur, R, ks) (*reinterpret_cast<const bf16x8*>( \
        ((ks) ? aP1 : aP0) + (cur) * 16384 + (R) * 1024))
#define RDB(cur, R, ks) (*reinterpret_cast<const bf16x8*>( \
        ((ks) ? bP1 : bP0) + (cur) * 16384 + (R) * 1024))

    bf16x8 alo[4][2], ahi[4][2], blo[2][2], bhi[2][2];

    // ---- prologue: t0 {AL13,AL24,B12,B34} + t1 {AL13,AL24} (12 gloads) ----
    gload_lds16(Ag,                   AsB + dsub);               // t0.AL1
    gload_lds16(Ag + 128 * D_MODEL,   AsB +  8192 + dsub);       // t0.AL3
    gload_lds16(Ag +  64 * D_MODEL,   AsB +  4096 + dsub);       // t0.AL2
    gload_lds16(Ag + 192 * D_MODEL,   AsB + 12288 + dsub);       // t0.AL4
    gload_lds16(Bg,                   BsB + dsub);               // t0.B1
    gload_lds16(Bg +  64 * D_MODEL,   BsB +  4096 + dsub);       // t0.B2
    gload_lds16(Bg + 128 * D_MODEL,   BsB +  8192 + dsub);       // t0.B3
    gload_lds16(Bg + 192 * D_MODEL,   BsB + 12288 + dsub);       // t0.B4
    gload_lds16(Ag +                64, AsB + 16384 + dsub);           // t1.AL1
    gload_lds16(Ag + 128 * D_MODEL + 64, AsB + 16384 +  8192 + dsub);  // t1.AL3
    gload_lds16(Ag +  64 * D_MODEL + 64, AsB + 16384 +  4096 + dsub);  // t1.AL2
    gload_lds16(Ag + 192 * D_MODEL + 64, AsB + 16384 + 12288 + dsub);  // t1.AL4
    VM_WAIT(4);                      // t0's 8 landed; t1's A halves still fly
    BAR();

    // pre-read tile0's alo + blo (consumed by kt=0 P1/Q1)
#pragma unroll
    for (int ii = 0; ii < 4; ++ii) { alo[ii][0] = RDA(0, ii, 0); alo[ii][1] = RDA(0, ii, 1); }
#pragma unroll
    for (int jj = 0; jj < 2; ++jj) { blo[jj][0] = RDB(0, jj, 0); blo[jj][1] = RDB(0, jj, 1); }

#pragma unroll 2
    for (int kt = 0; kt < KTILES; ++kt) {
        const int cur = kt & 1;
        bf16* An = AsB + cur * 16384;            // A stage target (t+2 -> cur)
        bf16* Bn = BsB + (cur ^ 1) * 16384;      // B stage target (t+1 -> nxt)
        const bf16* Ag2 = Ag + (kt + 2) * 64;
        const bf16* Bg1 = Bg + (kt + 1) * 64;

        // ---- P1: rd bhi(t); stage B12(t+1) ----
#pragma unroll
        for (int jj = 0; jj < 2; ++jj) { bhi[jj][0] = RDB(cur, 2 + jj, 0); bhi[jj][1] = RDB(cur, 2 + jj, 1); }
        if (kt + 1 < KTILES) {
            gload_lds16(Bg1,                Bn + dsub);
            gload_lds16(Bg1 + 64 * D_MODEL, Bn + 4096 + dsub);
        }
        BAR();
        LGKM_WAIT(4);
        __builtin_amdgcn_s_setprio(1);
#pragma unroll
        for (int ii = 0; ii < 4; ++ii)
#pragma unroll
            for (int jj = 0; jj < 2; ++jj)
#pragma unroll
                for (int ks = 0; ks < 2; ++ks)
                    acc[ii][jj] = __builtin_amdgcn_mfma_f32_16x16x32_bf16(alo[ii][ks], blo[jj][ks], acc[ii][jj], 0, 0, 0);
        __builtin_amdgcn_s_setprio(0);

        // ---- P2: rd ahi(t); stage B34(t+1); vmcnt(6) covers AL13(t+1) ----
#pragma unroll
        for (int ii = 0; ii < 4; ++ii) { ahi[ii][0] = RDA(cur, 4 + ii, 0); ahi[ii][1] = RDA(cur, 4 + ii, 1); }
        if (kt + 1 < KTILES) {
            gload_lds16(Bg1 + 128 * D_MODEL, Bn +  8192 + dsub);
            gload_lds16(Bg1 + 192 * D_MODEL, Bn + 12288 + dsub);
        }
        VM_WAIT(6);
        BAR();
        LGKM_WAIT(8);
        __builtin_amdgcn_s_setprio(1);
#pragma unroll
        for (int ii = 0; ii < 4; ++ii)
#pragma unroll
            for (int jj = 0; jj < 2; ++jj)
#pragma unroll
                for (int ks = 0; ks < 2; ++ks)
                    acc[ii][2 + jj] = __builtin_amdgcn_mfma_f32_16x16x32_bf16(alo[ii][ks], bhi[jj][ks], acc[ii][2 + jj], 0, 0, 0);
        __builtin_amdgcn_s_setprio(0);

        // ---- P3: rd alo(t+1) from nxt; stage AL13(t+2) ----
        if (kt + 1 < KTILES) {
#pragma unroll
            for (int ii = 0; ii < 4; ++ii) { alo[ii][0] = RDA(cur ^ 1, ii, 0); alo[ii][1] = RDA(cur ^ 1, ii, 1); }
        }
        if (kt + 2 < KTILES) {
            gload_lds16(Ag2,                 An + dsub);
            gload_lds16(Ag2 + 128 * D_MODEL, An + 8192 + dsub);
        }
        BAR();
        if (kt + 1 < KTILES) { LGKM_WAIT(8); } else { LGKM_WAIT(0); }
        __builtin_amdgcn_s_setprio(1);
#pragma unroll
        for (int ii = 0; ii < 4; ++ii)
#pragma unroll
            for (int jj = 0; jj < 2; ++jj)
#pragma unroll
                for (int ks = 0; ks < 2; ++ks)
                    acc[4 + ii][2 + jj] = __builtin_amdgcn_mfma_f32_16x16x32_bf16(ahi[ii][ks], bhi[jj][ks], acc[4 + ii][2 + jj], 0, 0, 0);
        __builtin_amdgcn_s_setprio(0);

        // ---- P4: stage AL24(t+2); vmcnt(4); Q4; rd blo(t+1) ----
        if (kt + 2 < KTILES) {
            gload_lds16(Ag2 +  64 * D_MODEL, An +  4096 + dsub);
            gload_lds16(Ag2 + 192 * D_MODEL, An + 12288 + dsub);
        }
        if (kt < KTILES - 2) { VM_WAIT(4); } else { VM_WAIT(0); }
        BAR();
        LGKM_WAIT(8);
        __builtin_amdgcn_s_setprio(1);
#pragma unroll
        for (int ii = 0; ii < 4; ++ii)
#pragma unroll
            for (int jj = 0; jj < 2; ++jj)
#pragma unroll
                for (int ks = 0; ks < 2; ++ks)
                    acc[4 + ii][jj] = __builtin_amdgcn_mfma_f32_16x16x32_bf16(ahi[ii][ks], blo[jj][ks], acc[4 + ii][jj], 0, 0, 0);
        __builtin_amdgcn_s_setprio(0);
        if (kt + 1 < KTILES) {
#pragma unroll
            for (int jj = 0; jj < 2; ++jj) { blo[jj][0] = RDB(cur ^ 1, jj, 0); blo[jj][1] = RDB(cur ^ 1, jj, 1); }
        }
    }
#undef RDA
#undef RDB
}

// ---------------- K,V projections (ternary), one dispatch ----------------
__global__ __launch_bounds__(512, 2) void gemm256_proj(
    const bf16* __restrict__ A0, const bf16* __restrict__ A1,
    const bf16* __restrict__ W0, const bf16* __restrict__ W1,
    bf16* __restrict__ O0, bf16* __restrict__ O1)
{
    const bf16* A = blockIdx.y ? A1 : A0;
    const bf16* W = blockIdx.y ? W1 : W0;
    bf16* O       = blockIdx.y ? O1 : O0;

    __shared__ bf16 As[2][2][8192];
    __shared__ bf16 Bs[2][2][8192];
    int m0, n0;
    tile_coords256(blockIdx.x, m0, n0);

    f32x4 acc[8][4] = {};
    gemm256_core(A, W, &As[0][0][0], &Bs[0][0][0], m0, n0, acc);

    const int lane = threadIdx.x & 63, wave = threadIdx.x >> 6;
    const int wm = wave >> 2, wn = wave & 3;
    const int mf = lane & 15, quad = lane >> 4;
#pragma unroll
    for (int i = 0; i < 8; ++i)
#pragma unroll
        for (int j = 0; j < 4; ++j)
#pragma unroll
            for (int e = 0; e < 4; ++e) {
                const int row = m0 + wm * 128 + i * 16 + quad * 4 + e;
                const int col = n0 + wn * 64 + j * 16 + mf;
                const float v = acc[i][j][e];
                const float o = (v > 0.5f) ? 1.0f : ((v < -0.5f) ? -1.0f : 0.0f);
                O[(size_t)row * D_MODEL + col] = f2bf(o);
            }
}

// ---------------- merged: R projection (sigmoid) + recurrent scan ----------------
__global__ __launch_bounds__(512, 2) void rproj_scan_kernel(
    const bf16* __restrict__ XR, const bf16* __restrict__ WrB, bf16* __restrict__ RB,
    const bf16* __restrict__ K, const bf16* __restrict__ V,
    const float* __restrict__ dw, const float* __restrict__ S0,
    bf16* __restrict__ sall, float* __restrict__ sfinal)
{
    __shared__ __align__(16) char smem[131072];

    if (blockIdx.x < 256) {
        bf16* As = reinterpret_cast<bf16*>(smem);            // 64 KB
        bf16* Bs = reinterpret_cast<bf16*>(smem + 65536);    // 64 KB
        int m0, n0;
        tile_coords256(blockIdx.x, m0, n0);

        f32x4 acc[8][4] = {};
        gemm256_core(XR, WrB, As, Bs, m0, n0, acc);

        const int lane = threadIdx.x & 63, wave = threadIdx.x >> 6;
        const int wm = wave >> 2, wn = wave & 3;
        const int mf = lane & 15, quad = lane >> 4;
#pragma unroll
        for (int i = 0; i < 8; ++i)
#pragma unroll
            for (int j = 0; j < 4; ++j)
#pragma unroll
                for (int e = 0; e < 4; ++e) {
                    const int row = m0 + wm * 128 + i * 16 + quad * 4 + e;
                    const int col = n0 + wn * 64 + j * 16 + mf;
                    const float v = acc[i][j][e];
                    RB[(size_t)row * D_MODEL + col] = f2bf(1.0f / (1.0f + __expf(-v)));
                }
        return;
    }

    // ---------------- scan half ----------------
    unsigned int* kvp = reinterpret_cast<unsigned int*>(smem);        // [8][32][64] = 64 KB
    float* Lf = reinterpret_cast<float*>(smem + 65536);               // [8][64]
    float* P  = reinterpret_cast<float*>(smem + 65536 + 2048);        // [8][64]

    const int bid = blockIdx.x - 256;      // 0..255
    const int db  = bid & 15, b = bid >> 4;
    const int ch  = threadIdx.x & 63;      // channel within group
    const int q   = threadIdx.x >> 6;      // T-chunk 0..7
    const int d   = db * 64 + ch;

    const float dec = 1.0f / (1.0f + __expf(-dw[d]));
    float c128 = dec;
#pragma unroll
    for (int i = 0; i < 7; i++) c128 *= c128;   // dec^128

    const size_t base = ((size_t)b * SEQ + q * 128) * D_MODEL + d;

    // pass 1: local scan (zero-init), batched loads, pack kv into LDS
    float S = 0.f;
    size_t idx = base;
    for (int t = 0; t < 128; t += 4, idx += 4 * D_MODEL) {
        const float k0 = bf2f(K[idx]);
        const float v0 = bf2f(V[idx]);
        const float k1 = bf2f(K[idx + 1 * D_MODEL]);
        const float v1 = bf2f(V[idx + 1 * D_MODEL]);
        const float k2 = bf2f(K[idx + 2 * D_MODEL]);
        const float v2 = bf2f(V[idx + 2 * D_MODEL]);
        const float k3 = bf2f(K[idx + 3 * D_MODEL]);
        const float v3 = bf2f(V[idx + 3 * D_MODEL]);
        const float p0 = k0 * v0, p1 = k1 * v1, p2 = k2 * v2, p3 = k3 * v3;
        S = dec * S + p0;
        S = dec * S + p1;
        S = dec * S + p2;
        S = dec * S + p3;
        const unsigned int w =
            ((unsigned int)((int)p0 & 255)) |
            ((unsigned int)((int)p1 & 255) << 8) |
            ((unsigned int)((int)p2 & 255) << 16) |
            ((unsigned int)((int)p3 & 255) << 24);
        kvp[(q * 32 + (t >> 2)) * 64 + ch] = w;
    }

    Lf[q * 64 + ch] = S;
    __syncthreads();
    if (q == 0) {
        float p = S0[b * D_MODEL + d];      // true S_{-1}
        P[ch] = p;
#pragma unroll
        for (int j = 1; j < 8; ++j) {
            p = Lf[(j - 1) * 64 + ch] + c128 * p;
            P[j * 64 + ch] = p;
        }
        p = Lf[7 * 64 + ch] + c128 * p;
        sfinal[b * D_MODEL + d] = p;
    }
    __syncthreads();

    // pass 2: replay from LDS with true incoming carry, store
    float Sv = P[q * 64 + ch];
    idx = base;
    for (int t4 = 0; t4 < 32; ++t4) {
        const unsigned int pw = kvp[(q * 32 + t4) * 64 + ch];
#pragma unroll
        for (int j = 0; j < 4; ++j, idx += D_MODEL) {
            const float p = (float)((int)(pw << (24 - 8 * j)) >> 24);
            Sv = dec * Sv + p;
            sall[idx] = f2bf(Sv);
        }
    }
}

// ---------------- output GEMM with residual epilogue ----------------
__global__ __launch_bounds__(512, 2) void gemm256_out(
    const bf16* __restrict__ SA, const bf16* __restrict__ Wo,
    const bf16* __restrict__ R, const float* __restrict__ x, float* __restrict__ out)
{
    __shared__ bf16 As[2][2][8192];
    __shared__ bf16 Bs[2][2][8192];
    int m0, n0;
    tile_coords256(blockIdx.x, m0, n0);

    f32x4 acc[8][4] = {};
    gemm256_core(SA, Wo, &As[0][0][0], &Bs[0][0][0], m0, n0, acc);

    const int lane = threadIdx.x & 63, wave = threadIdx.x >> 6;
    const int wm = wave >> 2, wn = wave & 3;
    const int mf = lane & 15, quad = lane >> 4;
#pragma unroll
    for (int i = 0; i < 8; ++i)
#pragma unroll
        for (int j = 0; j < 4; ++j)
#pragma unroll
            for (int e = 0; e < 4; ++e) {
                const int row = m0 + wm * 128 + i * 16 + quad * 4 + e;
                const int col = n0 + wn * 64 + j * 16 + mf;
                const size_t o = (size_t)row * D_MODEL + col;
                out[o] = x[o] + bf2f(R[o]) * acc[i][j][e];
            }
}

extern "C" void kernel_launch(void* const* d_in, const int* in_sizes, int n_in,
                              void* d_out, int out_size, void* d_ws, size_t ws_size,
                              hipStream_t stream) {
    const float* x     = (const float*)d_in[0];
    const float* S0    = (const float*)d_in[1];
    const float* gamma = (const float*)d_in[2];
    const float* beta  = (const float*)d_in[3];
    const float* tmk   = (const float*)d_in[4];
    const float* tmv   = (const float*)d_in[5];
    const float* tmr   = (const float*)d_in[6];
    const float* dw    = (const float*)d_in[7];
    const float* Wk    = (const float*)d_in[8];
    const float* Wv    = (const float*)d_in[9];
    const float* Wr    = (const float*)d_in[10];
    const float* Wo    = (const float*)d_in[11];
    float* out = (float*)d_out;

    const int WN = D_MODEL * D_MODEL;             // 1048576
    const size_t MATN = (size_t)NROWS * D_MODEL;  // 16777216

    // 8 MB weights + 5 x 32 MB matrix slots = 168 MB
    bf16* wsb  = (bf16*)d_ws;
    bf16* Wk_b = wsb;
    bf16* Wv_b = Wk_b + WN;
    bf16* Wr_b = Wv_b + WN;
    bf16* Wo_b = Wr_b + WN;
    bf16* XK = Wo_b + WN;     // slot0: XK,  later RB (XK dead after gemm_kv)
    bf16* XV = XK + MATN;     // slot1: XV,  later SA (XV dead after gemm_kv)
    bf16* XR = XV + MATN;     // slot2: XR
    bf16* Kt = XR + MATN;     // slot3
    bf16* Vt = Kt + MATN;     // slot4
    bf16* RB = XK;
    bf16* SA = XV;

    conv_w4_kernel<<<dim3(128, 4), 256, 0, stream>>>(Wk, Wv, Wr, Wo, wsb);

    lnmix_kernel<<<NROWS / 4, 256, 0, stream>>>(x, gamma, beta, tmk, tmv, tmr, XK, XV, XR);

    // K and V projections in one dispatch (independent blocks)
    gemm256_proj<<<dim3(256, 2), 512, 0, stream>>>(XK, XV, Wk_b, Wv_b, Kt, Vt);

    // merged: R projection (XK dead -> RB slot0) + scan (XV dead -> SA slot1)
    rproj_scan_kernel<<<512, 512, 0, stream>>>(XR, Wr_b, RB, Kt, Vt, dw, S0, SA, out + MATN);

    gemm256_out<<<256, 512, 0, stream>>>(SA, Wo_b, RB, x, out);
}

// Round 6
// 282.309 us; speedup vs baseline: 1.2406x; 1.2406x over previous
//
#include <hip/hip_runtime.h>
#include <hip/hip_bf16.h>
#include <math.h>

#define D_MODEL 1024
#define SEQ 1024
#define BATCH 16
#define NROWS (BATCH * SEQ)   // 16384
#define KT8 8                 // K-tiles of 128 fp8

typedef float f32x4 __attribute__((ext_vector_type(4)));
typedef int   i32x4 __attribute__((ext_vector_type(4)));
typedef int   i32x8 __attribute__((ext_vector_type(8)));
typedef __bf16 bf16x4 __attribute__((ext_vector_type(4)));
typedef __hip_bfloat16 bf16;
typedef unsigned char u8;

__device__ __forceinline__ float bf2f(bf16 v) { return __bfloat162float(v); }
__device__ __forceinline__ bf16 f2bf(float v) { return __float2bfloat16(v); }

__device__ __forceinline__ void gload_lds16(const u8* g, u8* l) {
    __builtin_amdgcn_global_load_lds(
        (const __attribute__((address_space(1))) void*)g,
        (__attribute__((address_space(3))) void*)l, 16, 0, 0);
}

// pack 4 floats -> 4 fp8 e4m3 bytes (OCP on gfx950)
__device__ __forceinline__ int pk_fp8x4(float a, float b, float c, float d) {
    int r = __builtin_amdgcn_cvt_pk_fp8_f32(a, b, 0, false);
    r = __builtin_amdgcn_cvt_pk_fp8_f32(c, d, r, true);
    return r;
}

// 1024 blocks -> 8 XCDs x 128: each XCD a 16-row M-band swept over 8 N-tiles.
__device__ __forceinline__ void tile_coords128(int lin, int& m0, int& n0) {
    const int xcd = lin & 7;
    const int loc = lin >> 3;            // 0..127
    m0 = (xcd * 16 + (loc & 15)) * 128;
    n0 = (loc >> 4) * 128;
}

// ---------------- all 4 weights fp32 -> fp8, one dispatch ----------------
__global__ void conv_w4_kernel(const float* __restrict__ s0, const float* __restrict__ s1,
                               const float* __restrict__ s2, const float* __restrict__ s3,
                               u8* __restrict__ dst) {
    const float* srcs[4] = {s0, s1, s2, s3};
    const float* src = srcs[blockIdx.y];
    int* d = reinterpret_cast<int*>(dst + (size_t)blockIdx.y * (D_MODEL * D_MODEL));
    int i = blockIdx.x * blockDim.x + threadIdx.x;
    const int stride = gridDim.x * blockDim.x;
    for (; i < (D_MODEL * D_MODEL) / 4; i += stride) {
        float4 f = reinterpret_cast<const float4*>(src)[i];
        d[i] = pk_fp8x4(f.x, f.y, f.z, f.w);
    }
}

// ---------------- fused LayerNorm + time-mix -> fp8 xk/xv/xr ----------------
__global__ __launch_bounds__(256) void lnmix_kernel(
    const float* __restrict__ x, const float* __restrict__ gamma, const float* __restrict__ beta,
    const float* __restrict__ tmk, const float* __restrict__ tmv, const float* __restrict__ tmr,
    u8* __restrict__ xk, u8* __restrict__ xv, u8* __restrict__ xr)
{
    const int wave = threadIdx.x >> 6, lane = threadIdx.x & 63;
    const int lb = (blockIdx.x & 7) * (gridDim.x >> 3) + (blockIdx.x >> 3);
    const int row = lb * 4 + wave;
    const int t = row & (SEQ - 1);
    const size_t base = (size_t)row * D_MODEL;

    float4 vc[4], vp[4];
    float sc = 0.f, sc2 = 0.f, sp = 0.f, sp2 = 0.f;
#pragma unroll
    for (int c = 0; c < 4; c++) {
        const int d = lane * 4 + c * 256;
        vc[c] = *reinterpret_cast<const float4*>(x + base + d);
        if (t == 0) { vp[c] = make_float4(0.f, 0.f, 0.f, 0.f); }
        else        { vp[c] = *reinterpret_cast<const float4*>(x + base - D_MODEL + d); }
        sc  += vc[c].x + vc[c].y + vc[c].z + vc[c].w;
        sc2 += vc[c].x * vc[c].x + vc[c].y * vc[c].y + vc[c].z * vc[c].z + vc[c].w * vc[c].w;
        sp  += vp[c].x + vp[c].y + vp[c].z + vp[c].w;
        sp2 += vp[c].x * vp[c].x + vp[c].y * vp[c].y + vp[c].z * vp[c].z + vp[c].w * vp[c].w;
    }
#pragma unroll
    for (int off = 1; off < 64; off <<= 1) {
        sc  += __shfl_xor(sc, off);
        sc2 += __shfl_xor(sc2, off);
        sp  += __shfl_xor(sp, off);
        sp2 += __shfl_xor(sp2, off);
    }
    const float muc = sc * (1.0f / D_MODEL);
    const float rc  = rsqrtf(sc2 * (1.0f / D_MODEL) - muc * muc + 1e-5f);
    const float mup = sp * (1.0f / D_MODEL);
    const float rp  = rsqrtf(sp2 * (1.0f / D_MODEL) - mup * mup + 1e-5f);

#pragma unroll
    for (int c = 0; c < 4; c++) {
        const int d = lane * 4 + c * 256;
        float4 g  = *reinterpret_cast<const float4*>(gamma + d);
        float4 b  = *reinterpret_cast<const float4*>(beta + d);
        float4 mk = *reinterpret_cast<const float4*>(tmk + d);
        float4 mv = *reinterpret_cast<const float4*>(tmv + d);
        float4 mr = *reinterpret_cast<const float4*>(tmr + d);
        float cn[4], pn[4];
        cn[0] = (vc[c].x - muc) * rc * g.x + b.x;
        cn[1] = (vc[c].y - muc) * rc * g.y + b.y;
        cn[2] = (vc[c].z - muc) * rc * g.z + b.z;
        cn[3] = (vc[c].w - muc) * rc * g.w + b.w;
        if (t == 0) { pn[0] = pn[1] = pn[2] = pn[3] = 0.f; }
        else {
            pn[0] = (vp[c].x - mup) * rp * g.x + b.x;
            pn[1] = (vp[c].y - mup) * rp * g.y + b.y;
            pn[2] = (vp[c].z - mup) * rp * g.z + b.z;
            pn[3] = (vp[c].w - mup) * rp * g.w + b.w;
        }
        const float mkv[4] = {mk.x, mk.y, mk.z, mk.w};
        const float mvv[4] = {mv.x, mv.y, mv.z, mv.w};
        const float mrv[4] = {mr.x, mr.y, mr.z, mr.w};
        float ok[4], ov[4], orr[4];
#pragma unroll
        for (int e = 0; e < 4; e++) {
            ok[e]  = mkv[e] * cn[e] + (1.0f - mkv[e]) * pn[e];
            ov[e]  = mvv[e] * cn[e] + (1.0f - mvv[e]) * pn[e];
            orr[e] = mrv[e] * cn[e] + (1.0f - mrv[e]) * pn[e];
        }
        *reinterpret_cast<int*>(xk + base + d) = pk_fp8x4(ok[0], ok[1], ok[2], ok[3]);
        *reinterpret_cast<int*>(xv + base + d) = pk_fp8x4(ov[0], ov[1], ov[2], ov[3]);
        *reinterpret_cast<int*>(xr + base + d) = pk_fp8x4(orr[0], orr[1], orr[2], orr[3]);
    }
}

// ============================================================================
// 128x128 fp8 MX GEMM core (m97/m148 structure): BK=128 fp8 (128 B rows),
// 256 threads / 4 waves (2Mx2N), single-buffered 16KB+16KB LDS, per K-tile:
// sync; 8x global_load_lds; sync; 16 ds_read_b128 pairs; 16 mfma_scale K=128.
// 16B-chunk XOR swizzle (row&7) on both stage-source and read -> conflict-free.
// A-frag: lane holds A[row=lane&15][k=quad*32 .. +31] (32 B, 8 VGPR). Scale=1.0
// (e8m0 127). C/D: row=quad*4+e, col=mf (shape-determined, dtype-independent).
// ============================================================================
__device__ __forceinline__ void gemm128_fp8_core(
    const u8* __restrict__ A, const u8* __restrict__ W,
    u8* __restrict__ As, u8* __restrict__ Bs,
    int m0, int n0, f32x4 (&acc)[4][4])
{
    const int tid  = threadIdx.x;
    const int wave = tid >> 6, lane = tid & 63;
    const int wm = wave >> 1, wn = wave & 1;
    const int mf = lane & 15, quad = lane >> 4;
    const int srow = tid >> 3;                         // 0..31
    const int sw = ((tid & 7) ^ (srow & 7)) * 16;      // pre-swizzled source chunk (bytes)

    const u8* Ag = A + (size_t)(m0 + srow) * D_MODEL + sw;
    const u8* Bg = W + (size_t)(n0 + srow) * D_MODEL + sw;

    // fragment base pointers (all reads become base + imm offset)
    const int swz0 = ((2 * quad)     ^ (mf & 7)) * 16;
    const int swz1 = ((2 * quad + 1) ^ (mf & 7)) * 16;
    const u8* aB0 = As + (wm * 64 + mf) * 128 + swz0;
    const u8* aB1 = As + (wm * 64 + mf) * 128 + swz1;
    const u8* bB0 = Bs + (wn * 64 + mf) * 128 + swz0;
    const u8* bB1 = Bs + (wn * 64 + mf) * 128 + swz1;

#pragma unroll 1
    for (int kt = 0; kt < KT8; ++kt) {
        __syncthreads();
#pragma unroll
        for (int g = 0; g < 4; ++g) {
            gload_lds16(Ag + (size_t)g * 32 * D_MODEL + kt * 128, As + g * 4096 + wave * 1024);
            gload_lds16(Bg + (size_t)g * 32 * D_MODEL + kt * 128, Bs + g * 4096 + wave * 1024);
        }
        __syncthreads();

        i32x8 af[4], bf[4];
#pragma unroll
        for (int i = 0; i < 4; ++i) {
            i32x4 lo = *reinterpret_cast<const i32x4*>(aB0 + i * 2048);
            i32x4 hi = *reinterpret_cast<const i32x4*>(aB1 + i * 2048);
            af[i] = __builtin_shufflevector(lo, hi, 0, 1, 2, 3, 4, 5, 6, 7);
        }
#pragma unroll
        for (int j = 0; j < 4; ++j) {
            i32x4 lo = *reinterpret_cast<const i32x4*>(bB0 + j * 2048);
            i32x4 hi = *reinterpret_cast<const i32x4*>(bB1 + j * 2048);
            bf[j] = __builtin_shufflevector(lo, hi, 0, 1, 2, 3, 4, 5, 6, 7);
        }
#pragma unroll
        for (int i = 0; i < 4; ++i)
#pragma unroll
            for (int j = 0; j < 4; ++j)
                acc[i][j] = __builtin_amdgcn_mfma_scale_f32_16x16x128_f8f6f4(
                    af[i], bf[j], acc[i][j], 0, 0, 0, 127, 0, 127);
    }
}

// ---------------- K,V projections (ternary -> int8), one dispatch ----------------
__global__ __launch_bounds__(256) void gemm128_kv(
    const u8* __restrict__ A0, const u8* __restrict__ A1,
    const u8* __restrict__ W0, const u8* __restrict__ W1,
    char* __restrict__ O0, char* __restrict__ O1)
{
    const u8* A = blockIdx.y ? A1 : A0;
    const u8* W = blockIdx.y ? W1 : W0;
    char* O     = blockIdx.y ? O1 : O0;

    __shared__ __align__(16) u8 As[16384];
    __shared__ __align__(16) u8 Bs[16384];
    int m0, n0;
    tile_coords128(blockIdx.x, m0, n0);

    f32x4 acc[4][4] = {};
    gemm128_fp8_core(A, W, As, Bs, m0, n0, acc);

    const int lane = threadIdx.x & 63, wave = threadIdx.x >> 6;
    const int wm = wave >> 1, wn = wave & 1;
    const int mf = lane & 15, quad = lane >> 4;
#pragma unroll
    for (int i = 0; i < 4; ++i)
#pragma unroll
        for (int j = 0; j < 4; ++j)
#pragma unroll
            for (int e = 0; e < 4; ++e) {
                const int row = m0 + wm * 64 + i * 16 + quad * 4 + e;
                const int col = n0 + wn * 64 + j * 16 + mf;
                const float v = acc[i][j][e];
                O[(size_t)row * D_MODEL + col] = (v > 0.5f) ? 1 : ((v < -0.5f) ? -1 : 0);
            }
}

// ---------------- merged: scan (blocks 0..255) + R projection (blocks 256..1279) ----
// Scan: int8 K,V; kv ternary packed 2-bit in LDS (16 KB); pass2 replays from LDS,
// writes SA as fp8. Scan blocks first so they overlap the R GEMM on the CUs.
__global__ __launch_bounds__(256) void rscan_kernel(
    const u8* __restrict__ XR, const u8* __restrict__ WrB, bf16* __restrict__ RB,
    const char* __restrict__ K8, const char* __restrict__ V8,
    const float* __restrict__ dw, const float* __restrict__ S0,
    u8* __restrict__ sall, float* __restrict__ sfinal)
{
    __shared__ __align__(16) u8 smem[32768];

    if (blockIdx.x >= 256) {
        u8* As = smem;
        u8* Bs = smem + 16384;
        int m0, n0;
        tile_coords128(blockIdx.x - 256, m0, n0);

        f32x4 acc[4][4] = {};
        gemm128_fp8_core(XR, WrB, As, Bs, m0, n0, acc);

        const int lane = threadIdx.x & 63, wave = threadIdx.x >> 6;
        const int wm = wave >> 1, wn = wave & 1;
        const int mf = lane & 15, quad = lane >> 4;
#pragma unroll
        for (int i = 0; i < 4; ++i)
#pragma unroll
            for (int j = 0; j < 4; ++j)
#pragma unroll
                for (int e = 0; e < 4; ++e) {
                    const int row = m0 + wm * 64 + i * 16 + quad * 4 + e;
                    const int col = n0 + wn * 64 + j * 16 + mf;
                    RB[(size_t)row * D_MODEL + col] = f2bf(1.0f / (1.0f + __expf(-acc[i][j][e])));
                }
        return;
    }

    // ---------------- scan ----------------
    unsigned int* kvp = reinterpret_cast<unsigned int*>(smem);         // [4][16][64] = 16 KB
    float* Lf = reinterpret_cast<float*>(smem + 16384);                // [4][64]
    float* P  = reinterpret_cast<float*>(smem + 16384 + 1024);         // [4][64]

    const int bid = blockIdx.x;            // 0..255
    const int db  = bid & 15, b = bid >> 4;
    const int ch  = threadIdx.x & 63;
    const int q   = threadIdx.x >> 6;      // T-chunk 0..3
    const int d   = db * 64 + ch;

    const float dec = 1.0f / (1.0f + __expf(-dw[d]));
    float c256 = dec;
#pragma unroll
    for (int i = 0; i < 8; i++) c256 *= c256;   // dec^256

    const size_t base = ((size_t)b * SEQ + q * 256) * D_MODEL + d;

    // pass 1: local scan, batched int8 loads, 2-bit pack into LDS
    float S = 0.f;
    size_t idx = base;
    unsigned int w = 0;
    for (int t = 0; t < 256; t += 4, idx += 4 * D_MODEL) {
        const int k0 = K8[idx];
        const int v0 = V8[idx];
        const int k1 = K8[idx + 1 * D_MODEL];
        const int v1 = V8[idx + 1 * D_MODEL];
        const int k2 = K8[idx + 2 * D_MODEL];
        const int v2 = V8[idx + 2 * D_MODEL];
        const int k3 = K8[idx + 3 * D_MODEL];
        const int v3 = V8[idx + 3 * D_MODEL];
        const int p0 = k0 * v0, p1 = k1 * v1, p2 = k2 * v2, p3 = k3 * v3;
        S = dec * S + (float)p0;
        S = dec * S + (float)p1;
        S = dec * S + (float)p2;
        S = dec * S + (float)p3;
        const int sh = 2 * (t & 15);
        w |= ((unsigned int)(p0 + 1) << sh) | ((unsigned int)(p1 + 1) << (sh + 2)) |
             ((unsigned int)(p2 + 1) << (sh + 4)) | ((unsigned int)(p3 + 1) << (sh + 6));
        if ((t & 15) == 12) { kvp[(q * 16 + (t >> 4)) * 64 + ch] = w; w = 0; }
    }

    Lf[q * 64 + ch] = S;
    __syncthreads();
    if (q == 0) {
        float p = S0[b * D_MODEL + d];      // true S_{-1}
        P[ch] = p;
        p = Lf[0 * 64 + ch] + c256 * p; P[1 * 64 + ch] = p;
        p = Lf[1 * 64 + ch] + c256 * p; P[2 * 64 + ch] = p;
        p = Lf[2 * 64 + ch] + c256 * p; P[3 * 64 + ch] = p;
        p = Lf[3 * 64 + ch] + c256 * p;
        sfinal[b * D_MODEL + d] = p;
    }
    __syncthreads();

    // pass 2: replay from LDS with true incoming carry, store fp8
    float Sv = P[q * 64 + ch];
    idx = base;
    for (int t16 = 0; t16 < 16; ++t16) {
        const unsigned int pw = kvp[(q * 16 + t16) * 64 + ch];
#pragma unroll
        for (int j = 0; j < 16; ++j, idx += D_MODEL) {
            const float p = (float)((int)((pw >> (2 * j)) & 3) - 1);
            Sv = dec * Sv + p;
            const int enc = __builtin_amdgcn_cvt_pk_fp8_f32(Sv, 0.f, 0, false);
            sall[idx] = (u8)(enc & 255);
        }
    }
}

// ---------------- output GEMM with residual epilogue ----------------
__global__ __launch_bounds__(256) void gemm128_out(
    const u8* __restrict__ SA, const u8* __restrict__ Wo,
    const bf16* __restrict__ R, const float* __restrict__ x, float* __restrict__ out)
{
    __shared__ __align__(16) u8 As[16384];
    __shared__ __align__(16) u8 Bs[16384];
    int m0, n0;
    tile_coords128(blockIdx.x, m0, n0);

    f32x4 acc[4][4] = {};
    gemm128_fp8_core(SA, Wo, As, Bs, m0, n0, acc);

    const int lane = threadIdx.x & 63, wave = threadIdx.x >> 6;
    const int wm = wave >> 1, wn = wave & 1;
    const int mf = lane & 15, quad = lane >> 4;
#pragma unroll
    for (int i = 0; i < 4; ++i)
#pragma unroll
        for (int j = 0; j < 4; ++j)
#pragma unroll
            for (int e = 0; e < 4; ++e) {
                const int row = m0 + wm * 64 + i * 16 + quad * 4 + e;
                const int col = n0 + wn * 64 + j * 16 + mf;
                const size_t o = (size_t)row * D_MODEL + col;
                out[o] = x[o] + bf2f(R[o]) * acc[i][j][e];
            }
}

extern "C" void kernel_launch(void* const* d_in, const int* in_sizes, int n_in,
                              void* d_out, int out_size, void* d_ws, size_t ws_size,
                              hipStream_t stream) {
    const float* x     = (const float*)d_in[0];
    const float* S0    = (const float*)d_in[1];
    const float* gamma = (const float*)d_in[2];
    const float* beta  = (const float*)d_in[3];
    const float* tmk   = (const float*)d_in[4];
    const float* tmv   = (const float*)d_in[5];
    const float* tmr   = (const float*)d_in[6];
    const float* dw    = (const float*)d_in[7];
    const float* Wk    = (const float*)d_in[8];
    const float* Wv    = (const float*)d_in[9];
    const float* Wr    = (const float*)d_in[10];
    const float* Wo    = (const float*)d_in[11];
    float* out = (float*)d_out;

    const int WN = D_MODEL * D_MODEL;             // 1 MB fp8 per weight
    const size_t MATN = (size_t)NROWS * D_MODEL;  // 16 MB per fp8/int8 matrix

    u8* ws   = (u8*)d_ws;
    u8* Wk8  = ws;
    u8* Wv8  = Wk8 + WN;
    u8* Wr8  = Wv8 + WN;
    u8* Wo8  = Wr8 + WN;
    u8* XK8  = Wo8 + WN;
    u8* XV8  = XK8 + MATN;
    u8* XR8  = XV8 + MATN;
    char* Kt8 = (char*)(XR8 + MATN);
    char* Vt8 = Kt8 + MATN;
    u8* SA8  = (u8*)(Vt8 + MATN);
    bf16* RB = (bf16*)(SA8 + MATN);               // 32 MB bf16

    conv_w4_kernel<<<dim3(256, 4), 256, 0, stream>>>(Wk, Wv, Wr, Wo, ws);

    lnmix_kernel<<<NROWS / 4, 256, 0, stream>>>(x, gamma, beta, tmk, tmv, tmr, XK8, XV8, XR8);

    // K and V projections (ternary -> int8), one dispatch
    gemm128_kv<<<dim3(1024, 2), 256, 0, stream>>>(XK8, XV8, Wk8, Wv8, Kt8, Vt8);

    // merged: scan (256 blocks, overlaps) + R projection (1024 blocks)
    rscan_kernel<<<1280, 256, 0, stream>>>(XR8, Wr8, RB, Kt8, Vt8, dw, S0, SA8, out + MATN);

    gemm128_out<<<1024, 256, 0, stream>>>(SA8, Wo8, RB, x, out);
}

// Round 7
// 270.221 us; speedup vs baseline: 1.2961x; 1.0447x over previous
//
#include <hip/hip_runtime.h>
#include <hip/hip_bf16.h>
#include <math.h>

#define D_MODEL 1024
#define SEQ 1024
#define BATCH 16
#define NROWS (BATCH * SEQ)   // 16384
#define KT8 8                 // K-tiles of 128 fp8

typedef float f32x4 __attribute__((ext_vector_type(4)));
typedef int   i32x4 __attribute__((ext_vector_type(4)));
typedef int   i32x8 __attribute__((ext_vector_type(8)));
typedef __hip_bfloat16 bf16;
typedef unsigned char u8;

__device__ __forceinline__ float bf2f(bf16 v) { return __bfloat162float(v); }
__device__ __forceinline__ bf16 f2bf(float v) { return __float2bfloat16(v); }

__device__ __forceinline__ void gload_lds16(const u8* g, u8* l) {
    __builtin_amdgcn_global_load_lds(
        (const __attribute__((address_space(1))) void*)g,
        (__attribute__((address_space(3))) void*)l, 16, 0, 0);
}

// pack 4 floats -> 4 fp8 e4m3 bytes (OCP on gfx950)
__device__ __forceinline__ int pk_fp8x4(float a, float b, float c, float d) {
    int r = __builtin_amdgcn_cvt_pk_fp8_f32(a, b, 0, false);
    r = __builtin_amdgcn_cvt_pk_fp8_f32(c, d, r, true);
    return r;
}

// 1024 blocks -> 8 XCDs x 128: each XCD a 16-row M-band swept over 8 N-tiles.
__device__ __forceinline__ void tile_coords128(int lin, int& m0, int& n0) {
    const int xcd = lin & 7;
    const int loc = lin >> 3;            // 0..127
    m0 = (xcd * 16 + (loc & 15)) * 128;
    n0 = (loc >> 4) * 128;
}

// ---------------- all 4 weights fp32 -> fp8, one dispatch ----------------
__global__ void conv_w4_kernel(const float* __restrict__ s0, const float* __restrict__ s1,
                               const float* __restrict__ s2, const float* __restrict__ s3,
                               u8* __restrict__ dst) {
    const float* srcs[4] = {s0, s1, s2, s3};
    const float* src = srcs[blockIdx.y];
    int* d = reinterpret_cast<int*>(dst + (size_t)blockIdx.y * (D_MODEL * D_MODEL));
    int i = blockIdx.x * blockDim.x + threadIdx.x;
    const int stride = gridDim.x * blockDim.x;
    for (; i < (D_MODEL * D_MODEL) / 4; i += stride) {
        float4 f = reinterpret_cast<const float4*>(src)[i];
        d[i] = pk_fp8x4(f.x, f.y, f.z, f.w);
    }
}

// ---------------- fused LayerNorm + time-mix -> fp8 xk/xv/xr ----------------
__global__ __launch_bounds__(256) void lnmix_kernel(
    const float* __restrict__ x, const float* __restrict__ gamma, const float* __restrict__ beta,
    const float* __restrict__ tmk, const float* __restrict__ tmv, const float* __restrict__ tmr,
    u8* __restrict__ xk, u8* __restrict__ xv, u8* __restrict__ xr)
{
    const int wave = threadIdx.x >> 6, lane = threadIdx.x & 63;
    const int lb = (blockIdx.x & 7) * (gridDim.x >> 3) + (blockIdx.x >> 3);
    const int row = lb * 4 + wave;
    const int t = row & (SEQ - 1);
    const size_t base = (size_t)row * D_MODEL;

    float4 vc[4], vp[4];
    float sc = 0.f, sc2 = 0.f, sp = 0.f, sp2 = 0.f;
#pragma unroll
    for (int c = 0; c < 4; c++) {
        const int d = lane * 4 + c * 256;
        vc[c] = *reinterpret_cast<const float4*>(x + base + d);
        if (t == 0) { vp[c] = make_float4(0.f, 0.f, 0.f, 0.f); }
        else        { vp[c] = *reinterpret_cast<const float4*>(x + base - D_MODEL + d); }
        sc  += vc[c].x + vc[c].y + vc[c].z + vc[c].w;
        sc2 += vc[c].x * vc[c].x + vc[c].y * vc[c].y + vc[c].z * vc[c].z + vc[c].w * vc[c].w;
        sp  += vp[c].x + vp[c].y + vp[c].z + vp[c].w;
        sp2 += vp[c].x * vp[c].x + vp[c].y * vp[c].y + vp[c].z * vp[c].z + vp[c].w * vp[c].w;
    }
#pragma unroll
    for (int off = 1; off < 64; off <<= 1) {
        sc  += __shfl_xor(sc, off);
        sc2 += __shfl_xor(sc2, off);
        sp  += __shfl_xor(sp, off);
        sp2 += __shfl_xor(sp2, off);
    }
    const float muc = sc * (1.0f / D_MODEL);
    const float rc  = rsqrtf(sc2 * (1.0f / D_MODEL) - muc * muc + 1e-5f);
    const float mup = sp * (1.0f / D_MODEL);
    const float rp  = rsqrtf(sp2 * (1.0f / D_MODEL) - mup * mup + 1e-5f);

#pragma unroll
    for (int c = 0; c < 4; c++) {
        const int d = lane * 4 + c * 256;
        float4 g  = *reinterpret_cast<const float4*>(gamma + d);
        float4 b  = *reinterpret_cast<const float4*>(beta + d);
        float4 mk = *reinterpret_cast<const float4*>(tmk + d);
        float4 mv = *reinterpret_cast<const float4*>(tmv + d);
        float4 mr = *reinterpret_cast<const float4*>(tmr + d);
        float cn[4], pn[4];
        cn[0] = (vc[c].x - muc) * rc * g.x + b.x;
        cn[1] = (vc[c].y - muc) * rc * g.y + b.y;
        cn[2] = (vc[c].z - muc) * rc * g.z + b.z;
        cn[3] = (vc[c].w - muc) * rc * g.w + b.w;
        if (t == 0) { pn[0] = pn[1] = pn[2] = pn[3] = 0.f; }
        else {
            pn[0] = (vp[c].x - mup) * rp * g.x + b.x;
            pn[1] = (vp[c].y - mup) * rp * g.y + b.y;
            pn[2] = (vp[c].z - mup) * rp * g.z + b.z;
            pn[3] = (vp[c].w - mup) * rp * g.w + b.w;
        }
        const float mkv[4] = {mk.x, mk.y, mk.z, mk.w};
        const float mvv[4] = {mv.x, mv.y, mv.z, mv.w};
        const float mrv[4] = {mr.x, mr.y, mr.z, mr.w};
        float ok[4], ov[4], orr[4];
#pragma unroll
        for (int e = 0; e < 4; e++) {
            ok[e]  = mkv[e] * cn[e] + (1.0f - mkv[e]) * pn[e];
            ov[e]  = mvv[e] * cn[e] + (1.0f - mvv[e]) * pn[e];
            orr[e] = mrv[e] * cn[e] + (1.0f - mrv[e]) * pn[e];
        }
        *reinterpret_cast<int*>(xk + base + d) = pk_fp8x4(ok[0], ok[1], ok[2], ok[3]);
        *reinterpret_cast<int*>(xv + base + d) = pk_fp8x4(ov[0], ov[1], ov[2], ov[3]);
        *reinterpret_cast<int*>(xr + base + d) = pk_fp8x4(orr[0], orr[1], orr[2], orr[3]);
    }
}

// ============================================================================
// 128x128 fp8 MX GEMM core. R7 change: conflict-free chunk permutation.
// Data chunk c (16B) of row r stored at LDS position g(c)^(r&7), where
// g(c)=((c&1)<<2)|(c>>1). Read of fragment half s (data chunk 2q+s) is then at
// position (s*4+quad)^(mf&7) -- byte-identical to the bf16 core's proven
// zero-conflict pattern. Stage source chunk: c = ginv((tid&7)^(srow&7)),
// ginv(y)=((y&3)<<1)|(y>>2); LDS dest stays linear (global_load_lds rule).
// ============================================================================
__device__ __forceinline__ void gemm128_fp8_core(
    const u8* __restrict__ A, const u8* __restrict__ W,
    u8* __restrict__ As, u8* __restrict__ Bs,
    int m0, int n0, f32x4 (&acc)[4][4])
{
    const int tid  = threadIdx.x;
    const int wave = tid >> 6, lane = tid & 63;
    const int wm = wave >> 1, wn = wave & 1;
    const int mf = lane & 15, quad = lane >> 4;
    const int srow = tid >> 3;                         // 0..31
    const int u  = (tid & 7) ^ (srow & 7);
    const int sw = (((u & 3) << 1) | (u >> 2)) * 16;   // source data chunk (bytes)

    const u8* Ag = A + (size_t)(m0 + srow) * D_MODEL + sw;
    const u8* Bg = W + (size_t)(n0 + srow) * D_MODEL + sw;

    // fragment base pointers: position (s*4+quad)^(mf&7)
    const int swz0 = ((quad)     ^ (mf & 7)) * 16;
    const int swz1 = ((4 + quad) ^ (mf & 7)) * 16;
    const u8* aB0 = As + (wm * 64 + mf) * 128 + swz0;
    const u8* aB1 = As + (wm * 64 + mf) * 128 + swz1;
    const u8* bB0 = Bs + (wn * 64 + mf) * 128 + swz0;
    const u8* bB1 = Bs + (wn * 64 + mf) * 128 + swz1;

#pragma unroll 1
    for (int kt = 0; kt < KT8; ++kt) {
        __syncthreads();
#pragma unroll
        for (int g = 0; g < 4; ++g) {
            gload_lds16(Ag + (size_t)g * 32 * D_MODEL + kt * 128, As + g * 4096 + wave * 1024);
            gload_lds16(Bg + (size_t)g * 32 * D_MODEL + kt * 128, Bs + g * 4096 + wave * 1024);
        }
        __syncthreads();

        i32x8 af[4], bf[4];
#pragma unroll
        for (int i = 0; i < 4; ++i) {
            i32x4 lo = *reinterpret_cast<const i32x4*>(aB0 + i * 2048);
            i32x4 hi = *reinterpret_cast<const i32x4*>(aB1 + i * 2048);
            af[i] = __builtin_shufflevector(lo, hi, 0, 1, 2, 3, 4, 5, 6, 7);
        }
#pragma unroll
        for (int j = 0; j < 4; ++j) {
            i32x4 lo = *reinterpret_cast<const i32x4*>(bB0 + j * 2048);
            i32x4 hi = *reinterpret_cast<const i32x4*>(bB1 + j * 2048);
            bf[j] = __builtin_shufflevector(lo, hi, 0, 1, 2, 3, 4, 5, 6, 7);
        }
#pragma unroll
        for (int i = 0; i < 4; ++i)
#pragma unroll
            for (int j = 0; j < 4; ++j)
                acc[i][j] = __builtin_amdgcn_mfma_scale_f32_16x16x128_f8f6f4(
                    af[i], bf[j], acc[i][j], 0, 0, 0, 127, 0, 127);
    }
}

// ---------------- K,V projections (ternary -> int8), one dispatch ----------------
__global__ __launch_bounds__(256) void gemm128_kv(
    const u8* __restrict__ A0, const u8* __restrict__ A1,
    const u8* __restrict__ W0, const u8* __restrict__ W1,
    char* __restrict__ O0, char* __restrict__ O1)
{
    const u8* A = blockIdx.y ? A1 : A0;
    const u8* W = blockIdx.y ? W1 : W0;
    char* O     = blockIdx.y ? O1 : O0;

    __shared__ __align__(16) u8 As[16384];
    __shared__ __align__(16) u8 Bs[16384];
    int m0, n0;
    tile_coords128(blockIdx.x, m0, n0);

    f32x4 acc[4][4] = {};
    gemm128_fp8_core(A, W, As, Bs, m0, n0, acc);

    const int lane = threadIdx.x & 63, wave = threadIdx.x >> 6;
    const int wm = wave >> 1, wn = wave & 1;
    const int mf = lane & 15, quad = lane >> 4;
#pragma unroll
    for (int i = 0; i < 4; ++i)
#pragma unroll
        for (int j = 0; j < 4; ++j)
#pragma unroll
            for (int e = 0; e < 4; ++e) {
                const int row = m0 + wm * 64 + i * 16 + quad * 4 + e;
                const int col = n0 + wn * 64 + j * 16 + mf;
                const float v = acc[i][j][e];
                O[(size_t)row * D_MODEL + col] = (v > 0.5f) ? 1 : ((v < -0.5f) ? -1 : 0);
            }
}

// ---------------- standalone scan: 8 T-chunks x 128 steps, 512 threads ----------------
// int8 K,V; ternary kv packed 2-bit in LDS (16 KB); pass 2 replays from LDS,
// writes SA fp8; cross-chunk carry via dec^128.
__global__ __launch_bounds__(512) void scan_kernel(
    const char* __restrict__ K8, const char* __restrict__ V8,
    const float* __restrict__ dw, const float* __restrict__ S0,
    u8* __restrict__ sall, float* __restrict__ sfinal)
{
    __shared__ unsigned int kvp[8][8][64];   // 16 KB: [chunk][word][ch]
    __shared__ float Lf[8][64];
    __shared__ float P[8][64];

    const int bid = blockIdx.x;            // 0..255
    const int db  = bid & 15, b = bid >> 4;
    const int ch  = threadIdx.x & 63;
    const int q   = threadIdx.x >> 6;      // T-chunk 0..7
    const int d   = db * 64 + ch;

    const float dec = 1.0f / (1.0f + __expf(-dw[d]));
    float c128 = dec;
#pragma unroll
    for (int i = 0; i < 7; i++) c128 *= c128;   // dec^128

    const size_t base = ((size_t)b * SEQ + q * 128) * D_MODEL + d;

    // pass 1: local scan (zero-init), batched int8 loads, 2-bit pack into LDS
    float S = 0.f;
    size_t idx = base;
    unsigned int w = 0;
    for (int t = 0; t < 128; t += 4, idx += 4 * D_MODEL) {
        const int k0 = K8[idx];
        const int v0 = V8[idx];
        const int k1 = K8[idx + 1 * D_MODEL];
        const int v1 = V8[idx + 1 * D_MODEL];
        const int k2 = K8[idx + 2 * D_MODEL];
        const int v2 = V8[idx + 2 * D_MODEL];
        const int k3 = K8[idx + 3 * D_MODEL];
        const int v3 = V8[idx + 3 * D_MODEL];
        const int p0 = k0 * v0, p1 = k1 * v1, p2 = k2 * v2, p3 = k3 * v3;
        S = dec * S + (float)p0;
        S = dec * S + (float)p1;
        S = dec * S + (float)p2;
        S = dec * S + (float)p3;
        const int sh = 2 * (t & 15);
        w |= ((unsigned int)(p0 + 1) << sh) | ((unsigned int)(p1 + 1) << (sh + 2)) |
             ((unsigned int)(p2 + 1) << (sh + 4)) | ((unsigned int)(p3 + 1) << (sh + 6));
        if ((t & 15) == 12) { kvp[q][t >> 4][ch] = w; w = 0; }
    }

    Lf[q][ch] = S;
    __syncthreads();
    if (q == 0) {
        float p = S0[b * D_MODEL + d];      // true S_{-1}
        P[0][ch] = p;
#pragma unroll
        for (int j = 1; j < 8; ++j) {
            p = Lf[j - 1][ch] + c128 * p;
            P[j][ch] = p;
        }
        p = Lf[7][ch] + c128 * p;
        sfinal[b * D_MODEL + d] = p;
    }
    __syncthreads();

    // pass 2: replay from LDS with true incoming carry, store fp8
    float Sv = P[q][ch];
    idx = base;
    for (int t16 = 0; t16 < 8; ++t16) {
        const unsigned int pw = kvp[q][t16][ch];
#pragma unroll
        for (int j = 0; j < 16; ++j, idx += D_MODEL) {
            const float p = (float)((int)((pw >> (2 * j)) & 3) - 1);
            Sv = dec * Sv + p;
            const int enc = __builtin_amdgcn_cvt_pk_fp8_f32(Sv, 0.f, 0, false);
            sall[idx] = (u8)(enc & 255);
        }
    }
}

// ---------------- fused output: R = sigmoid(XR.Wr^T) tile, then out = x + R*(SA.Wo^T) ----
__global__ __launch_bounds__(256, 2) void gemm128_outR(
    const u8* __restrict__ XR, const u8* __restrict__ Wr,
    const u8* __restrict__ SA, const u8* __restrict__ Wo,
    const float* __restrict__ x, float* __restrict__ out)
{
    __shared__ __align__(16) u8 As[16384];
    __shared__ __align__(16) u8 Bs[16384];
    int m0, n0;
    tile_coords128(blockIdx.x, m0, n0);

    f32x4 accR[4][4] = {};
    gemm128_fp8_core(XR, Wr, As, Bs, m0, n0, accR);
#pragma unroll
    for (int i = 0; i < 4; ++i)
#pragma unroll
        for (int j = 0; j < 4; ++j)
#pragma unroll
            for (int e = 0; e < 4; ++e)
                accR[i][j][e] = 1.0f / (1.0f + __expf(-accR[i][j][e]));

    f32x4 acc[4][4] = {};
    gemm128_fp8_core(SA, Wo, As, Bs, m0, n0, acc);

    const int lane = threadIdx.x & 63, wave = threadIdx.x >> 6;
    const int wm = wave >> 1, wn = wave & 1;
    const int mf = lane & 15, quad = lane >> 4;
#pragma unroll
    for (int i = 0; i < 4; ++i)
#pragma unroll
        for (int j = 0; j < 4; ++j)
#pragma unroll
            for (int e = 0; e < 4; ++e) {
                const int row = m0 + wm * 64 + i * 16 + quad * 4 + e;
                const int col = n0 + wn * 64 + j * 16 + mf;
                const size_t o = (size_t)row * D_MODEL + col;
                out[o] = x[o] + accR[i][j][e] * acc[i][j][e];
            }
}

extern "C" void kernel_launch(void* const* d_in, const int* in_sizes, int n_in,
                              void* d_out, int out_size, void* d_ws, size_t ws_size,
                              hipStream_t stream) {
    const float* x     = (const float*)d_in[0];
    const float* S0    = (const float*)d_in[1];
    const float* gamma = (const float*)d_in[2];
    const float* beta  = (const float*)d_in[3];
    const float* tmk   = (const float*)d_in[4];
    const float* tmv   = (const float*)d_in[5];
    const float* tmr   = (const float*)d_in[6];
    const float* dw    = (const float*)d_in[7];
    const float* Wk    = (const float*)d_in[8];
    const float* Wv    = (const float*)d_in[9];
    const float* Wr    = (const float*)d_in[10];
    const float* Wo    = (const float*)d_in[11];
    float* out = (float*)d_out;

    const int WN = D_MODEL * D_MODEL;             // 1 MB fp8 per weight
    const size_t MATN = (size_t)NROWS * D_MODEL;  // 16 MB per fp8/int8 matrix

    u8* ws   = (u8*)d_ws;
    u8* Wk8  = ws;
    u8* Wv8  = Wk8 + WN;
    u8* Wr8  = Wv8 + WN;
    u8* Wo8  = Wr8 + WN;
    u8* XK8  = Wo8 + WN;
    u8* XV8  = XK8 + MATN;
    u8* XR8  = XV8 + MATN;
    char* Kt8 = (char*)(XR8 + MATN);
    char* Vt8 = Kt8 + MATN;
    u8* SA8  = (u8*)(Vt8 + MATN);

    conv_w4_kernel<<<dim3(256, 4), 256, 0, stream>>>(Wk, Wv, Wr, Wo, ws);

    lnmix_kernel<<<NROWS / 4, 256, 0, stream>>>(x, gamma, beta, tmk, tmv, tmr, XK8, XV8, XR8);

    // K and V projections (ternary -> int8), one dispatch
    gemm128_kv<<<dim3(1024, 2), 256, 0, stream>>>(XK8, XV8, Wk8, Wv8, Kt8, Vt8);

    // standalone scan (SA fp8 + S_final)
    scan_kernel<<<256, 512, 0, stream>>>(Kt8, Vt8, dw, S0, SA8, out + MATN);

    // fused R-projection + output GEMM + residual
    gemm128_outR<<<1024, 256, 0, stream>>>(XR8, Wr8, SA8, Wo8, x, out);
}

// Round 8
// 268.615 us; speedup vs baseline: 1.3039x; 1.0060x over previous
//
#include <hip/hip_runtime.h>
#include <hip/hip_bf16.h>
#include <math.h>

#define D_MODEL 1024
#define SEQ 1024
#define BATCH 16
#define NROWS (BATCH * SEQ)   // 16384
#define KT8 8                 // K-tiles of 128 fp8

typedef float f32x4 __attribute__((ext_vector_type(4)));
typedef int   i32x4 __attribute__((ext_vector_type(4)));
typedef int   i32x8 __attribute__((ext_vector_type(8)));
typedef __hip_bfloat16 bf16;
typedef unsigned char u8;

__device__ __forceinline__ float bf2f(bf16 v) { return __bfloat162float(v); }
__device__ __forceinline__ bf16 f2bf(float v) { return __float2bfloat16(v); }

__device__ __forceinline__ void gload_lds16(const u8* g, u8* l) {
    __builtin_amdgcn_global_load_lds(
        (const __attribute__((address_space(1))) void*)g,
        (__attribute__((address_space(3))) void*)l, 16, 0, 0);
}

// pack 4 floats -> 4 fp8 e4m3 bytes (OCP on gfx950)
__device__ __forceinline__ int pk_fp8x4(float a, float b, float c, float d) {
    int r = __builtin_amdgcn_cvt_pk_fp8_f32(a, b, 0, false);
    r = __builtin_amdgcn_cvt_pk_fp8_f32(c, d, r, true);
    return r;
}

// 1024 blocks -> 8 XCDs x 128: each XCD a 16-row M-band swept over 8 N-tiles.
__device__ __forceinline__ void tile_coords128(int lin, int& m0, int& n0) {
    const int xcd = lin & 7;
    const int loc = lin >> 3;            // 0..127
    m0 = (xcd * 16 + (loc & 15)) * 128;
    n0 = (loc >> 4) * 128;
}

// ---------------- all 4 weights fp32 -> fp8, one dispatch ----------------
__global__ void conv_w4_kernel(const float* __restrict__ s0, const float* __restrict__ s1,
                               const float* __restrict__ s2, const float* __restrict__ s3,
                               u8* __restrict__ dst) {
    const float* srcs[4] = {s0, s1, s2, s3};
    const float* src = srcs[blockIdx.y];
    int* d = reinterpret_cast<int*>(dst + (size_t)blockIdx.y * (D_MODEL * D_MODEL));
    int i = blockIdx.x * blockDim.x + threadIdx.x;
    const int stride = gridDim.x * blockDim.x;
    for (; i < (D_MODEL * D_MODEL) / 4; i += stride) {
        float4 f = reinterpret_cast<const float4*>(src)[i];
        d[i] = pk_fp8x4(f.x, f.y, f.z, f.w);
    }
}

// ---------------- fused LayerNorm + time-mix -> fp8 xk/xv/xr ----------------
__global__ __launch_bounds__(256) void lnmix_kernel(
    const float* __restrict__ x, const float* __restrict__ gamma, const float* __restrict__ beta,
    const float* __restrict__ tmk, const float* __restrict__ tmv, const float* __restrict__ tmr,
    u8* __restrict__ xk, u8* __restrict__ xv, u8* __restrict__ xr)
{
    const int wave = threadIdx.x >> 6, lane = threadIdx.x & 63;
    const int lb = (blockIdx.x & 7) * (gridDim.x >> 3) + (blockIdx.x >> 3);
    const int row = lb * 4 + wave;
    const int t = row & (SEQ - 1);
    const size_t base = (size_t)row * D_MODEL;

    float4 vc[4], vp[4];
    float sc = 0.f, sc2 = 0.f, sp = 0.f, sp2 = 0.f;
#pragma unroll
    for (int c = 0; c < 4; c++) {
        const int d = lane * 4 + c * 256;
        vc[c] = *reinterpret_cast<const float4*>(x + base + d);
        if (t == 0) { vp[c] = make_float4(0.f, 0.f, 0.f, 0.f); }
        else        { vp[c] = *reinterpret_cast<const float4*>(x + base - D_MODEL + d); }
        sc  += vc[c].x + vc[c].y + vc[c].z + vc[c].w;
        sc2 += vc[c].x * vc[c].x + vc[c].y * vc[c].y + vc[c].z * vc[c].z + vc[c].w * vc[c].w;
        sp  += vp[c].x + vp[c].y + vp[c].z + vp[c].w;
        sp2 += vp[c].x * vp[c].x + vp[c].y * vp[c].y + vp[c].z * vp[c].z + vp[c].w * vp[c].w;
    }
#pragma unroll
    for (int off = 1; off < 64; off <<= 1) {
        sc  += __shfl_xor(sc, off);
        sc2 += __shfl_xor(sc2, off);
        sp  += __shfl_xor(sp, off);
        sp2 += __shfl_xor(sp2, off);
    }
    const float muc = sc * (1.0f / D_MODEL);
    const float rc  = rsqrtf(sc2 * (1.0f / D_MODEL) - muc * muc + 1e-5f);
    const float mup = sp * (1.0f / D_MODEL);
    const float rp  = rsqrtf(sp2 * (1.0f / D_MODEL) - mup * mup + 1e-5f);

#pragma unroll
    for (int c = 0; c < 4; c++) {
        const int d = lane * 4 + c * 256;
        float4 g  = *reinterpret_cast<const float4*>(gamma + d);
        float4 b  = *reinterpret_cast<const float4*>(beta + d);
        float4 mk = *reinterpret_cast<const float4*>(tmk + d);
        float4 mv = *reinterpret_cast<const float4*>(tmv + d);
        float4 mr = *reinterpret_cast<const float4*>(tmr + d);
        float cn[4], pn[4];
        cn[0] = (vc[c].x - muc) * rc * g.x + b.x;
        cn[1] = (vc[c].y - muc) * rc * g.y + b.y;
        cn[2] = (vc[c].z - muc) * rc * g.z + b.z;
        cn[3] = (vc[c].w - muc) * rc * g.w + b.w;
        if (t == 0) { pn[0] = pn[1] = pn[2] = pn[3] = 0.f; }
        else {
            pn[0] = (vp[c].x - mup) * rp * g.x + b.x;
            pn[1] = (vp[c].y - mup) * rp * g.y + b.y;
            pn[2] = (vp[c].z - mup) * rp * g.z + b.z;
            pn[3] = (vp[c].w - mup) * rp * g.w + b.w;
        }
        const float mkv[4] = {mk.x, mk.y, mk.z, mk.w};
        const float mvv[4] = {mv.x, mv.y, mv.z, mv.w};
        const float mrv[4] = {mr.x, mr.y, mr.z, mr.w};
        float ok[4], ov[4], orr[4];
#pragma unroll
        for (int e = 0; e < 4; e++) {
            ok[e]  = mkv[e] * cn[e] + (1.0f - mkv[e]) * pn[e];
            ov[e]  = mvv[e] * cn[e] + (1.0f - mvv[e]) * pn[e];
            orr[e] = mrv[e] * cn[e] + (1.0f - mrv[e]) * pn[e];
        }
        *reinterpret_cast<int*>(xk + base + d) = pk_fp8x4(ok[0], ok[1], ok[2], ok[3]);
        *reinterpret_cast<int*>(xv + base + d) = pk_fp8x4(ov[0], ov[1], ov[2], ov[3]);
        *reinterpret_cast<int*>(xr + base + d) = pk_fp8x4(orr[0], orr[1], orr[2], orr[3]);
    }
}

// ============================================================================
// DUAL 128x128 fp8 MX GEMM core: two independent GEMMs (A0.W0^T, A1.W1^T) over
// the same (m0,n0) tile, interleaved in ONE K-loop. Per kt: 16 global_load_lds
// (4 tiles x 4 groups) + 32 ds_read_b128 + 32 mfma -- halves barriers/FLOP and
// doubles in-flight VMEM vs the single core. 64 KB LDS.
// Conflict-free chunk permutation (R7, measured 0 conflicts): data chunk c of
// row r at position g(c)^(r&7), g(c)=((c&1)<<2)|(c>>1); read of fragment half
// s at position (s*4+quad)^(mf&7). LDS dest linear (global_load_lds rule).
// ============================================================================
__device__ __forceinline__ void gemm128_fp8_dual(
    const u8* __restrict__ A0, const u8* __restrict__ W0,
    const u8* __restrict__ A1, const u8* __restrict__ W1,
    u8* __restrict__ lds,
    int m0, int n0, f32x4 (&acc0)[4][4], f32x4 (&acc1)[4][4])
{
    const int tid  = threadIdx.x;
    const int wave = tid >> 6, lane = tid & 63;
    const int wm = wave >> 1, wn = wave & 1;
    const int mf = lane & 15, quad = lane >> 4;
    const int srow = tid >> 3;                         // 0..31
    const int u  = (tid & 7) ^ (srow & 7);
    const int sw = (((u & 3) << 1) | (u >> 2)) * 16;   // source data chunk (bytes)

    const u8* A0g = A0 + (size_t)(m0 + srow) * D_MODEL + sw;
    const u8* B0g = W0 + (size_t)(n0 + srow) * D_MODEL + sw;
    const u8* A1g = A1 + (size_t)(m0 + srow) * D_MODEL + sw;
    const u8* B1g = W1 + (size_t)(n0 + srow) * D_MODEL + sw;

    u8* As0 = lds;
    u8* Bs0 = lds + 16384;
    u8* As1 = lds + 32768;
    u8* Bs1 = lds + 49152;

    // fragment base offsets: position (s*4+quad)^(mf&7)
    const int swz0 = ((quad)     ^ (mf & 7)) * 16;
    const int swz1 = ((4 + quad) ^ (mf & 7)) * 16;
    const int aRow = (wm * 64 + mf) * 128;
    const int bRow = (wn * 64 + mf) * 128;

#pragma unroll 1
    for (int kt = 0; kt < KT8; ++kt) {
        __syncthreads();
#pragma unroll
        for (int g = 0; g < 4; ++g) {
            const size_t go = (size_t)g * 32 * D_MODEL + kt * 128;
            const int lo = g * 4096 + wave * 1024;
            gload_lds16(A0g + go, As0 + lo);
            gload_lds16(B0g + go, Bs0 + lo);
            gload_lds16(A1g + go, As1 + lo);
            gload_lds16(B1g + go, Bs1 + lo);
        }
        __syncthreads();

        i32x8 af[4], bf[4];
        // ---- GEMM 0 ----
#pragma unroll
        for (int i = 0; i < 4; ++i) {
            i32x4 lo = *reinterpret_cast<const i32x4*>(As0 + aRow + i * 2048 + swz0);
            i32x4 hi = *reinterpret_cast<const i32x4*>(As0 + aRow + i * 2048 + swz1);
            af[i] = __builtin_shufflevector(lo, hi, 0, 1, 2, 3, 4, 5, 6, 7);
        }
#pragma unroll
        for (int j = 0; j < 4; ++j) {
            i32x4 lo = *reinterpret_cast<const i32x4*>(Bs0 + bRow + j * 2048 + swz0);
            i32x4 hi = *reinterpret_cast<const i32x4*>(Bs0 + bRow + j * 2048 + swz1);
            bf[j] = __builtin_shufflevector(lo, hi, 0, 1, 2, 3, 4, 5, 6, 7);
        }
#pragma unroll
        for (int i = 0; i < 4; ++i)
#pragma unroll
            for (int j = 0; j < 4; ++j)
                acc0[i][j] = __builtin_amdgcn_mfma_scale_f32_16x16x128_f8f6f4(
                    af[i], bf[j], acc0[i][j], 0, 0, 0, 127, 0, 127);
        // ---- GEMM 1 ----
#pragma unroll
        for (int i = 0; i < 4; ++i) {
            i32x4 lo = *reinterpret_cast<const i32x4*>(As1 + aRow + i * 2048 + swz0);
            i32x4 hi = *reinterpret_cast<const i32x4*>(As1 + aRow + i * 2048 + swz1);
            af[i] = __builtin_shufflevector(lo, hi, 0, 1, 2, 3, 4, 5, 6, 7);
        }
#pragma unroll
        for (int j = 0; j < 4; ++j) {
            i32x4 lo = *reinterpret_cast<const i32x4*>(Bs1 + bRow + j * 2048 + swz0);
            i32x4 hi = *reinterpret_cast<const i32x4*>(Bs1 + bRow + j * 2048 + swz1);
            bf[j] = __builtin_shufflevector(lo, hi, 0, 1, 2, 3, 4, 5, 6, 7);
        }
#pragma unroll
        for (int i = 0; i < 4; ++i)
#pragma unroll
            for (int j = 0; j < 4; ++j)
                acc1[i][j] = __builtin_amdgcn_mfma_scale_f32_16x16x128_f8f6f4(
                    af[i], bf[j], acc1[i][j], 0, 0, 0, 127, 0, 127);
    }
}

// ---------------- K and V projections in ONE K-loop (ternary -> int8) ----------------
__global__ __launch_bounds__(256, 2) void gemm128_kv(
    const u8* __restrict__ XK, const u8* __restrict__ Wk,
    const u8* __restrict__ XV, const u8* __restrict__ Wv,
    char* __restrict__ OK, char* __restrict__ OV)
{
    __shared__ __align__(16) u8 lds[65536];
    int m0, n0;
    tile_coords128(blockIdx.x, m0, n0);

    f32x4 acc0[4][4] = {}, acc1[4][4] = {};
    gemm128_fp8_dual(XK, Wk, XV, Wv, lds, m0, n0, acc0, acc1);

    const int lane = threadIdx.x & 63, wave = threadIdx.x >> 6;
    const int wm = wave >> 1, wn = wave & 1;
    const int mf = lane & 15, quad = lane >> 4;
#pragma unroll
    for (int i = 0; i < 4; ++i)
#pragma unroll
        for (int j = 0; j < 4; ++j)
#pragma unroll
            for (int e = 0; e < 4; ++e) {
                const int row = m0 + wm * 64 + i * 16 + quad * 4 + e;
                const int col = n0 + wn * 64 + j * 16 + mf;
                const size_t o = (size_t)row * D_MODEL + col;
                const float k = acc0[i][j][e];
                const float v = acc1[i][j][e];
                OK[o] = (k > 0.5f) ? 1 : ((k < -0.5f) ? -1 : 0);
                OV[o] = (v > 0.5f) ? 1 : ((v < -0.5f) ? -1 : 0);
            }
}

// ---------------- standalone scan: 8 T-chunks x 128 steps, 512 threads ----------------
__global__ __launch_bounds__(512) void scan_kernel(
    const char* __restrict__ K8, const char* __restrict__ V8,
    const float* __restrict__ dw, const float* __restrict__ S0,
    u8* __restrict__ sall, float* __restrict__ sfinal)
{
    __shared__ unsigned int kvp[8][8][64];   // 16 KB: [chunk][word][ch]
    __shared__ float Lf[8][64];
    __shared__ float P[8][64];

    const int bid = blockIdx.x;            // 0..255
    const int db  = bid & 15, b = bid >> 4;
    const int ch  = threadIdx.x & 63;
    const int q   = threadIdx.x >> 6;      // T-chunk 0..7
    const int d   = db * 64 + ch;

    const float dec = 1.0f / (1.0f + __expf(-dw[d]));
    float c128 = dec;
#pragma unroll
    for (int i = 0; i < 7; i++) c128 *= c128;   // dec^128

    const size_t base = ((size_t)b * SEQ + q * 128) * D_MODEL + d;

    // pass 1: local scan (zero-init), batched int8 loads, 2-bit pack into LDS
    float S = 0.f;
    size_t idx = base;
    unsigned int w = 0;
    for (int t = 0; t < 128; t += 4, idx += 4 * D_MODEL) {
        const int k0 = K8[idx];
        const int v0 = V8[idx];
        const int k1 = K8[idx + 1 * D_MODEL];
        const int v1 = V8[idx + 1 * D_MODEL];
        const int k2 = K8[idx + 2 * D_MODEL];
        const int v2 = V8[idx + 2 * D_MODEL];
        const int k3 = K8[idx + 3 * D_MODEL];
        const int v3 = V8[idx + 3 * D_MODEL];
        const int p0 = k0 * v0, p1 = k1 * v1, p2 = k2 * v2, p3 = k3 * v3;
        S = dec * S + (float)p0;
        S = dec * S + (float)p1;
        S = dec * S + (float)p2;
        S = dec * S + (float)p3;
        const int sh = 2 * (t & 15);
        w |= ((unsigned int)(p0 + 1) << sh) | ((unsigned int)(p1 + 1) << (sh + 2)) |
             ((unsigned int)(p2 + 1) << (sh + 4)) | ((unsigned int)(p3 + 1) << (sh + 6));
        if ((t & 15) == 12) { kvp[q][t >> 4][ch] = w; w = 0; }
    }

    Lf[q][ch] = S;
    __syncthreads();
    if (q == 0) {
        float p = S0[b * D_MODEL + d];      // true S_{-1}
        P[0][ch] = p;
#pragma unroll
        for (int j = 1; j < 8; ++j) {
            p = Lf[j - 1][ch] + c128 * p;
            P[j][ch] = p;
        }
        p = Lf[7][ch] + c128 * p;
        sfinal[b * D_MODEL + d] = p;
    }
    __syncthreads();

    // pass 2: replay from LDS with true incoming carry, store fp8
    float Sv = P[q][ch];
    idx = base;
    for (int t16 = 0; t16 < 8; ++t16) {
        const unsigned int pw = kvp[q][t16][ch];
#pragma unroll
        for (int j = 0; j < 16; ++j, idx += D_MODEL) {
            const float p = (float)((int)((pw >> (2 * j)) & 3) - 1);
            Sv = dec * Sv + p;
            const int enc = __builtin_amdgcn_cvt_pk_fp8_f32(Sv, 0.f, 0, false);
            sall[idx] = (u8)(enc & 255);
        }
    }
}

// ---------------- fused output: R-GEMM + O-GEMM in one K-loop + residual ----------------
__global__ __launch_bounds__(256, 2) void gemm128_outR(
    const u8* __restrict__ XR, const u8* __restrict__ Wr,
    const u8* __restrict__ SA, const u8* __restrict__ Wo,
    const float* __restrict__ x, float* __restrict__ out)
{
    __shared__ __align__(16) u8 lds[65536];
    int m0, n0;
    tile_coords128(blockIdx.x, m0, n0);

    f32x4 accR[4][4] = {}, acc[4][4] = {};
    gemm128_fp8_dual(XR, Wr, SA, Wo, lds, m0, n0, accR, acc);

    const int lane = threadIdx.x & 63, wave = threadIdx.x >> 6;
    const int wm = wave >> 1, wn = wave & 1;
    const int mf = lane & 15, quad = lane >> 4;
#pragma unroll
    for (int i = 0; i < 4; ++i)
#pragma unroll
        for (int j = 0; j < 4; ++j)
#pragma unroll
            for (int e = 0; e < 4; ++e) {
                const int row = m0 + wm * 64 + i * 16 + quad * 4 + e;
                const int col = n0 + wn * 64 + j * 16 + mf;
                const size_t o = (size_t)row * D_MODEL + col;
                const float r = 1.0f / (1.0f + __expf(-accR[i][j][e]));
                out[o] = x[o] + r * acc[i][j][e];
            }
}

extern "C" void kernel_launch(void* const* d_in, const int* in_sizes, int n_in,
                              void* d_out, int out_size, void* d_ws, size_t ws_size,
                              hipStream_t stream) {
    const float* x     = (const float*)d_in[0];
    const float* S0    = (const float*)d_in[1];
    const float* gamma = (const float*)d_in[2];
    const float* beta  = (const float*)d_in[3];
    const float* tmk   = (const float*)d_in[4];
    const float* tmv   = (const float*)d_in[5];
    const float* tmr   = (const float*)d_in[6];
    const float* dw    = (const float*)d_in[7];
    const float* Wk    = (const float*)d_in[8];
    const float* Wv    = (const float*)d_in[9];
    const float* Wr    = (const float*)d_in[10];
    const float* Wo    = (const float*)d_in[11];
    float* out = (float*)d_out;

    const int WN = D_MODEL * D_MODEL;             // 1 MB fp8 per weight
    const size_t MATN = (size_t)NROWS * D_MODEL;  // 16 MB per fp8/int8 matrix

    u8* ws   = (u8*)d_ws;
    u8* Wk8  = ws;
    u8* Wv8  = Wk8 + WN;
    u8* Wr8  = Wv8 + WN;
    u8* Wo8  = Wr8 + WN;
    u8* XK8  = Wo8 + WN;
    u8* XV8  = XK8 + MATN;
    u8* XR8  = XV8 + MATN;
    char* Kt8 = (char*)(XR8 + MATN);
    char* Vt8 = Kt8 + MATN;
    u8* SA8  = (u8*)(Vt8 + MATN);

    conv_w4_kernel<<<dim3(256, 4), 256, 0, stream>>>(Wk, Wv, Wr, Wo, ws);

    lnmix_kernel<<<NROWS / 4, 256, 0, stream>>>(x, gamma, beta, tmk, tmv, tmr, XK8, XV8, XR8);

    // K and V projections interleaved in one K-loop (ternary -> int8)
    gemm128_kv<<<1024, 256, 0, stream>>>(XK8, Wk8, XV8, Wv8, Kt8, Vt8);

    // standalone scan (SA fp8 + S_final)
    scan_kernel<<<256, 512, 0, stream>>>(Kt8, Vt8, dw, S0, SA8, out + MATN);

    // fused R-projection + output GEMM interleaved + residual
    gemm128_outR<<<1024, 256, 0, stream>>>(XR8, Wr8, SA8, Wo8, x, out);
}